// Round 11
// baseline (2060.996 us; speedup 1.0000x reference)
//
#include <hip/hip_runtime.h>
#include <hip/hip_bf16.h>
#include <cstddef>

// Problem constants (fixed by the harness shapes)
#define NINP 4096
#define NHID 512
#define G4   2048   // 4*NHID
#define NTOK 50257
#define BSZ  32
#define T_ENC 80
#define T_DEC 40
#define DQ   2      // hbuf ring depth per layer

typedef __attribute__((ext_vector_type(4))) float  f32x4;
typedef __attribute__((ext_vector_type(4))) __bf16 bf16x4;
typedef __attribute__((ext_vector_type(8))) __bf16 bf16x8;

// ---------------------------------------------------------------------------
// XOR-swizzled byte offsets (row-major bf16 tiles, 16B-slot XOR row&7)
// ---------------------------------------------------------------------------
__device__ __forceinline__ int sw_off(int r, int k) {   // [rows][64] bf16
    return r * 128 + ((((k >> 3) ^ (r & 7)) << 4) | ((k & 7) << 1));
}
__device__ __forceinline__ int swA(int r, int k) {      // [rows][128] bf16
    return r * 256 + ((((k >> 3) ^ (r & 7)) << 4) | ((k & 7) << 1));
}
__device__ __forceinline__ int sw512(int r, int k) {    // [rows][512] bf16
    return r * 1024 + ((((k >> 3) ^ (r & 7)) << 4) | ((k & 7) << 1));
}

__device__ __forceinline__ void split4(const float4& v, bf16x4& h, bf16x4& l) {
    float a0 = v.x, a1 = v.y, a2 = v.z, a3 = v.w;
    __bf16 h0 = (__bf16)a0, h1 = (__bf16)a1, h2 = (__bf16)a2, h3 = (__bf16)a3;
    h[0] = h0; h[1] = h1; h[2] = h2; h[3] = h3;
    l[0] = (__bf16)(a0 - (float)h0);
    l[1] = (__bf16)(a1 - (float)h1);
    l[2] = (__bf16)(a2 - (float)h2);
    l[3] = (__bf16)(a3 - (float)h3);
}

__device__ __forceinline__ bf16x4 hi4(const float4& v) {
    bf16x4 h; h[0] = (__bf16)v.x; h[1] = (__bf16)v.y;
    h[2] = (__bf16)v.z; h[3] = (__bf16)v.w; return h;
}

__device__ __forceinline__ void split8(const float4& a, const float4& b,
                                       bf16x8& h, bf16x8& l) {
    float x[8] = {a.x, a.y, a.z, a.w, b.x, b.y, b.z, b.w};
    #pragma unroll
    for (int i = 0; i < 8; i++) {
        __bf16 hb = (__bf16)x[i];
        h[i] = hb; l[i] = (__bf16)(x[i] - (float)hb);
    }
}

__device__ __forceinline__ bf16x8 to_bf16x8(const float4& a, const float4& b) {
    bf16x8 r;
    r[0]=(__bf16)a.x; r[1]=(__bf16)a.y; r[2]=(__bf16)a.z; r[3]=(__bf16)a.w;
    r[4]=(__bf16)b.x; r[5]=(__bf16)b.y; r[6]=(__bf16)b.z; r[7]=(__bf16)b.w;
    return r;
}

__device__ __forceinline__ void unpack8(const uint4& a, const uint4& b,
                                        bf16x8& h, bf16x8& l) {
    unsigned u[8] = {a.x, a.y, a.z, a.w, b.x, b.y, b.z, b.w};
    union { unsigned short s; __bf16 v; } t;
    #pragma unroll
    for (int i = 0; i < 8; i++) {
        t.s = (unsigned short)(u[i] & 0xffff); h[i] = t.v;
        t.s = (unsigned short)(u[i] >> 16);    l[i] = t.v;
    }
}
__device__ __forceinline__ bf16x8 unpack_hi8(const uint4& a, const uint4& b) {
    unsigned u[8] = {a.x, a.y, a.z, a.w, b.x, b.y, b.z, b.w};
    union { unsigned short s; __bf16 v; } t;
    bf16x8 h;
    #pragma unroll
    for (int i = 0; i < 8; i++) { t.s = (unsigned short)(u[i] & 0xffff); h[i] = t.v; }
    return h;
}

__device__ __forceinline__ unsigned pack_hilo(float x) {
    __bf16 hb = (__bf16)x;
    float hf = (float)hb;
    __bf16 lb = (__bf16)(x - hf);
    union { __bf16 b; unsigned short s; } ch, cl;
    ch.b = hb; cl.b = lb;
    return (unsigned)ch.s | ((unsigned)cl.s << 16);
}

__device__ __forceinline__ float fast_sigmoid(float x) {
    return 1.f / (1.f + __expf(-x));
}
__device__ __forceinline__ float fast_tanh(float x) {
    return 1.f - 2.f / (__expf(2.f * x) + 1.f);
}

// ---------------------------------------------------------------------------
// Compensated bf16 MFMA GEMM (2-pass: Ah*Bh + Al*Bh; B hi-only):
// encoder input projection. (verified)
// ---------------------------------------------------------------------------
__global__ __launch_bounds__(256) void gemm_hilo(
    const float* __restrict__ A, int lda,
    const float* __restrict__ B, int ldb,
    const float* __restrict__ bias,
    float* __restrict__ Z, int ldz,
    int N, int K)
{
    __shared__ __align__(16) char lds[49152];
    const int tid  = threadIdx.x;
    const int bm   = blockIdx.y * 128;
    const int bn   = blockIdx.x * 128;
    const int wave = tid >> 6;
    const int lane = tid & 63;
    const int wm   = (wave >> 1) * 64;
    const int wn   = (wave & 1) * 64;
    const int lr   = lane & 15;
    const int kg   = lane >> 4;

    const int rr = tid >> 4;
    const int kk = (tid & 15) * 4;

    f32x4 acc[4][4] = {};

    for (int k0 = 0; k0 < K; k0 += 64) {
        float4 av[8], bv[8];
        #pragma unroll
        for (int i = 0; i < 8; i++) {
            int r = i * 16 + rr;
            av[i] = *(const float4*)&A[(size_t)(bm + r) * lda + k0 + kk];
            int rb = bn + r;
            if (rb < N)
                bv[i] = *(const float4*)&B[(size_t)rb * ldb + k0 + kk];
            else
                bv[i] = make_float4(0.f, 0.f, 0.f, 0.f);
        }
        __syncthreads();
        #pragma unroll
        for (int i = 0; i < 8; i++) {
            int r = i * 16 + rr;
            int off = sw_off(r, kk);
            bf16x4 h, l;
            split4(av[i], h, l);
            *(bf16x4*)(lds + off)         = h;
            *(bf16x4*)(lds + 16384 + off) = l;
            *(bf16x4*)(lds + 32768 + off) = hi4(bv[i]);
        }
        __syncthreads();
        #pragma unroll
        for (int ks = 0; ks < 2; ks++) {
            bf16x8 ah[4], al[4], bh[4];
            const int kbase = ks * 32 + kg * 8;
            #pragma unroll
            for (int f = 0; f < 4; f++) {
                int offA = sw_off(wm + f * 16 + lr, kbase);
                ah[f] = *(const bf16x8*)(lds + offA);
                al[f] = *(const bf16x8*)(lds + 16384 + offA);
                int offB = sw_off(wn + f * 16 + lr, kbase);
                bh[f] = *(const bf16x8*)(lds + 32768 + offB);
            }
            #pragma unroll
            for (int fm = 0; fm < 4; fm++)
                #pragma unroll
                for (int fn = 0; fn < 4; fn++) {
                    acc[fm][fn] = __builtin_amdgcn_mfma_f32_16x16x32_bf16(
                        ah[fm], bh[fn], acc[fm][fn], 0, 0, 0);
                    acc[fm][fn] = __builtin_amdgcn_mfma_f32_16x16x32_bf16(
                        al[fm], bh[fn], acc[fm][fn], 0, 0, 0);
                }
        }
    }

    #pragma unroll
    for (int fn = 0; fn < 4; fn++) {
        int col = bn + wn + fn * 16 + lr;
        if (col < N) {
            float bb = bias ? bias[col] : 0.f;
            #pragma unroll
            for (int fm = 0; fm < 4; fm++) {
                #pragma unroll
                for (int j = 0; j < 4; j++) {
                    int row = bm + wm + fm * 16 + kg * 4 + j;
                    Z[(size_t)row * ldz + col] = acc[fm][fn][j] + bb;
                }
            }
        }
    }
}

// ---------------------------------------------------------------------------
// Vocab projection: Z[1280][50257] = dec3h[1280][512](bf16) @ W_out^T + b_out.
// W_out panel staged once per block. (verified rounds 7-10)
// ---------------------------------------------------------------------------
__global__ __launch_bounds__(256, 1) void gemm_vocab(
    const __bf16* __restrict__ Ah,    // [1280][512] bf16
    const float* __restrict__ B,      // [50257][512] fp32
    const float* __restrict__ bias,   // [50257]
    float* __restrict__ Z)            // [1280][50257]
{
    __shared__ __align__(16) char lds[163840];  // B panel 128K | A tile 32K
    char* ldsB = lds;
    char* ldsA = lds + 131072;

    const int tid  = threadIdx.x;
    const int bn   = blockIdx.x * 128;
    const int wave = tid >> 6;
    const int lane = tid & 63;
    const int wm   = (wave >> 1) * 64;
    const int wn   = (wave & 1) * 64;
    const int lr   = lane & 15;
    const int kg   = lane >> 4;

    // ---- stage B panel once (fp32 -> bf16, swizzled) ----
    #pragma unroll 4
    for (int jj = 0; jj < 32; jj++) {
        int e = tid + jj * 256;           // 0..8191
        int row = e >> 6;                 // 0..127
        int k = (e & 63) * 8;             // 0..504
        int gr = bn + row;
        float4 v0, v1;
        if (gr < NTOK) {
            v0 = *(const float4*)&B[(size_t)gr * 512 + k];
            v1 = *(const float4*)&B[(size_t)gr * 512 + k + 4];
        } else {
            v0 = make_float4(0.f,0.f,0.f,0.f); v1 = v0;
        }
        *(bf16x8*)(ldsB + sw512(row, k)) = to_bf16x8(v0, v1);
    }

    float bb[4];
    #pragma unroll
    for (int fn = 0; fn < 4; fn++) {
        int col = bn + wn + fn * 16 + lr;
        bb[fn] = (col < NTOK) ? bias[col] : 0.f;
    }
    __syncthreads();

    for (int mt = 0; mt < 10; mt++) {
        f32x4 acc[4][4] = {};
        for (int k0 = 0; k0 < 4; k0++) {
            __syncthreads();   // WAR on A tile
            #pragma unroll
            for (int jj = 0; jj < 8; jj++) {
                int e = tid + jj * 256;       // 0..2047
                int row = e >> 4;             // 0..127
                int k = (e & 15) * 8;         // 0..120
                uint4 v = *(const uint4*)&Ah[(size_t)(mt * 128 + row) * 512 + k0 * 128 + k];
                *(uint4*)(ldsA + swA(row, k)) = v;
            }
            __syncthreads();
            #pragma unroll
            for (int ks = 0; ks < 4; ks++) {
                bf16x8 ah[4], bh[4];
                const int ka = ks * 32 + kg * 8;
                #pragma unroll
                for (int f = 0; f < 4; f++) {
                    ah[f] = *(const bf16x8*)(ldsA + swA(wm + f * 16 + lr, ka));
                    bh[f] = *(const bf16x8*)(ldsB + sw512(wn + f * 16 + lr, k0 * 128 + ka));
                }
                #pragma unroll
                for (int fm = 0; fm < 4; fm++)
                    #pragma unroll
                    for (int fn = 0; fn < 4; fn++)
                        acc[fm][fn] = __builtin_amdgcn_mfma_f32_16x16x32_bf16(
                            ah[fm], bh[fn], acc[fm][fn], 0, 0, 0);
            }
        }
        #pragma unroll
        for (int fn = 0; fn < 4; fn++) {
            int col = bn + wn + fn * 16 + lr;
            if (col < NTOK) {
                #pragma unroll
                for (int fm = 0; fm < 4; fm++) {
                    #pragma unroll
                    for (int j = 0; j < 4; j++) {
                        int row = mt * 128 + wm + fm * 16 + kg * 4 + j;
                        Z[(size_t)row * NTOK + col] = acc[fm][fn][j] + bb[fn];
                    }
                }
            }
        }
    }
}

// ---------------------------------------------------------------------------
// Fused 4-layer pipelined LSTM scan — ATOMIC-COUNTER dataflow sync.
// 256 blocks, 1/CU (160 KB LDS). Layer L = blockIdx>>6 runs its own t-loop.
// cnt[L] = total completed block-steps of layer L (monotonic).
// Start of step t, tid0 polls ONE loop over <=3 broadcast lines:
//   cnt[L]   >= 64*t      (all own-layer blocks finished t-1: h[t-1] ready,
//                          AND slot t&1's old h[t-2] fully consumed -> WAR ok)
//   cnt[L-1] >= 64*(t+1)  (upstream finished t: x=h_{L-1}[t] ready)   [L>0]
//   cnt[L+1] >= 64*(t-1)  (downstream finished t-2: consumed h[t-2])  [L<3]
// End of step: release fence + fetch_add(cnt[L],1). Two LLC round trips
// per step total (vs 4 in r9/r10's two-hop barrier).
// Deadlock-free: each wait references strictly earlier (t,L) progress.
// Gate-interleaved lane mapping (r8): wave's 16 cols = [i,f,g,o] x 4 jc ->
// gates via 3 __shfl_xor. h exchange: packed (hi|lo) u32, 2-slot ring (r9).
// LDS: A_hi 0..32K | A_lo 32K..64K | X_hi 64K..96K | Whh 96K..128K |
//      Wih 128K..160K.
// ---------------------------------------------------------------------------
__global__ __launch_bounds__(256, 1) void fused_scan(
    const float* __restrict__ Zx,
    const float* __restrict__ Whh_0, const float* __restrict__ bias_0,
    const float* __restrict__ Wih_1, const float* __restrict__ Whh_1,
    const float* __restrict__ bias_1,
    const float* __restrict__ Wih_2, const float* __restrict__ Whh_2,
    const float* __restrict__ bias_2e, const float* __restrict__ bias_2d,
    const float* __restrict__ Wih_3, const float* __restrict__ Whh_3,
    const float* __restrict__ bias_3,
    const float* __restrict__ hid1_h, const float* __restrict__ hid1_c,
    const float* __restrict__ hid2_h, const float* __restrict__ hid2_c,
    __bf16* __restrict__ dec3h,
    unsigned* hbuf,            // [4][DQ][32][512] packed (hi|lo) u32
    unsigned* cnt)             // [4], stride 32 u32 (128 B) apart
{
    __shared__ __align__(16) char lds[163840];

    const int tid  = threadIdx.x;
    const int L    = blockIdx.x >> 6;
    const int bidc = blockIdx.x & 63;
    const int wave = tid >> 6;
    const int lane = tid & 63;
    const int mh   = wave >> 1;    // batch half
    const int ng   = wave & 1;     // n-col group
    const int lr   = lane & 15;
    const int kg   = lane >> 4;
    const int lr3  = lr & 3;       // gate role: 0=i 1=f 2=g 3=o
    const int jcbase = bidc * 8;
    const int bq = tid >> 3;       // staging row 0..31
    const int aq = tid & 7;        // staging k-lane

    const float* Whh = (L==0)?Whh_0:(L==1)?Whh_1:(L==2)?Whh_2:Whh_3;
    const float* Wih = (L==1)?Wih_1:(L==2)?Wih_2:(L==3)?Wih_3:nullptr;
    const int ld_ih  = (L==2)?1024:512;
    const float* be  = (L==0)?bias_0:(L==1)?bias_1:(L==2)?bias_2e:bias_3;
    const float* bd  = (L==2)?bias_2d:be;
    const float* h0  = ((L<2)?hid1_h:hid2_h) + (L&1)*16384;
    const float* c0  = ((L<2)?hid1_c:hid2_c) + (L&1)*16384;
    unsigned* myb       = hbuf + (size_t)L*DQ*16384;
    const unsigned* xsb = hbuf + (size_t)(L>0 ? (L-1) : 0)*DQ*16384;

    // ---- stage weights into LDS (hi-only, gate-interleaved rows), once ----
    // LDS row n (0..31) <- weight row (n&3)*512 + jcbase + (n>>2)   [r8]
    {
        int wrow = (bq & 3) * 512 + jcbase + (bq >> 2);
        const float* wr = Whh + (size_t)wrow * 512;
        #pragma unroll
        for (int jj = 0; jj < 8; jj++) {
            int k = aq * 8 + jj * 64;
            *(bf16x8*)(lds + 98304 + sw512(bq, k)) =
                to_bf16x8(*(const float4*)(wr + k), *(const float4*)(wr + k + 4));
        }
        if (Wih) {
            const float* wr2 = Wih + (size_t)wrow * ld_ih;
            #pragma unroll
            for (int jj = 0; jj < 8; jj++) {
                int k = aq * 8 + jj * 64;
                *(bf16x8*)(lds + 131072 + sw512(bq, k)) =
                    to_bf16x8(*(const float4*)(wr2 + k), *(const float4*)(wr2 + k + 4));
            }
        }
    }

    // lane's output column: gate lr3, col = jcbase + ng*4 + (lr>>2)   [r8]
    const int hcol = jcbase + ng*4 + (lr >> 2);
    const int grow = lr3 * 512 + hcol;          // row in [2048] gate space
    const float bbe = be[grow];
    const float bbd = bd[grow];

    // c-state (meaningful on lr3==1 lanes; loaded by all)
    float cc[4];
    #pragma unroll
    for (int j = 0; j < 4; j++)
        cc[j] = c0[(mh*16 + kg*4 + j)*512 + hcol];

    const int rowA = mh*16 + lr;
    const int rowB = ng*16 + lr;

    for (int t = 0; t < 120; ++t) {
        // ---- combined dataflow poll: ONE loop, <=3 broadcast lines ----
        if (tid == 0) {
            const unsigned own = 64u * (unsigned)t;
            const unsigned up  = 64u * (unsigned)(t + 1);
            const unsigned dn  = (t >= 1) ? 64u * (unsigned)(t - 1) : 0u;
            for (;;) {
                bool ok = __hip_atomic_load(&cnt[L*32], __ATOMIC_RELAXED,
                                            __HIP_MEMORY_SCOPE_AGENT) >= own;
                if (L > 0)
                    ok &= __hip_atomic_load(&cnt[(L-1)*32], __ATOMIC_RELAXED,
                                            __HIP_MEMORY_SCOPE_AGENT) >= up;
                if (L < 3)
                    ok &= __hip_atomic_load(&cnt[(L+1)*32], __ATOMIC_RELAXED,
                                            __HIP_MEMORY_SCOPE_AGENT) >= dn;
                if (ok) break;
                __builtin_amdgcn_s_sleep(1);
            }
            __builtin_amdgcn_fence(__ATOMIC_ACQUIRE, "agent");
        }
        __syncthreads();

        // ---- Zx prefetch (L0 encoder only) ----
        float zx[4] = {0.f, 0.f, 0.f, 0.f};
        if (L == 0 && t < 80) {
            #pragma unroll
            for (int j = 0; j < 4; j++)
                zx[j] = Zx[(size_t)t*(BSZ*G4) + (mh*16+kg*4+j)*G4 + grow];
        }

        // ---- stage h (hi/lo) and x (hi) ----
        if (t == 0) {
            const float* hr = h0 + bq*512;
            #pragma unroll
            for (int jj = 0; jj < 8; jj++) {
                int k = aq*8 + jj*64;
                bf16x8 H, Lo;
                split8(*(const float4*)(hr+k), *(const float4*)(hr+k+4), H, Lo);
                int off = sw512(bq, k);
                *(bf16x8*)(lds + off)         = H;
                *(bf16x8*)(lds + 32768 + off) = Lo;
            }
        } else {
            const unsigned* hs = myb + (size_t)((t-1) & (DQ-1))*16384 + bq*512;
            #pragma unroll
            for (int jj = 0; jj < 8; jj++) {
                int k = aq*8 + jj*64;
                bf16x8 H, Lo;
                unpack8(*(const uint4*)(hs+k), *(const uint4*)(hs+k+4), H, Lo);
                int off = sw512(bq, k);
                *(bf16x8*)(lds + off)         = H;
                *(bf16x8*)(lds + 32768 + off) = Lo;
            }
        }
        if (L > 0) {
            const unsigned* xp = xsb + (size_t)(t & (DQ-1))*16384 + bq*512;
            #pragma unroll
            for (int jj = 0; jj < 8; jj++) {
                int k = aq*8 + jj*64;
                *(bf16x8*)(lds + 65536 + sw512(bq, k)) =
                    unpack_hi8(*(const uint4*)(xp+k), *(const uint4*)(xp+k+4));
            }
        }
        __syncthreads();

        // ---- MFMA: z = h@Whh^T (2-pass) + x@Wih^T (hi) ----
        f32x4 accA = {0.f,0.f,0.f,0.f}, accB = {0.f,0.f,0.f,0.f};
        #pragma unroll
        for (int ks = 0; ks < 16; ++ks) {
            int k = ks*32 + kg*8;
            int offA = sw512(rowA, k);
            bf16x8 ah = *(const bf16x8*)(lds + offA);
            bf16x8 al = *(const bf16x8*)(lds + 32768 + offA);
            bf16x8 bh = *(const bf16x8*)(lds + 98304 + sw512(rowB, k));
            accA = __builtin_amdgcn_mfma_f32_16x16x32_bf16(ah, bh, accA, 0,0,0);
            accB = __builtin_amdgcn_mfma_f32_16x16x32_bf16(al, bh, accB, 0,0,0);
        }
        if (L > 0) {
            #pragma unroll
            for (int ks = 0; ks < 16; ++ks) {
                int k = ks*32 + kg*8;
                bf16x8 ax = *(const bf16x8*)(lds + 65536 + sw512(rowA, k));
                bf16x8 bi = *(const bf16x8*)(lds + 131072 + sw512(rowB, k));
                accA = __builtin_amdgcn_mfma_f32_16x16x32_bf16(ax, bi, accA, 0,0,0);
            }
        }

        // ---- gates via lane shuffles (i,f,g,o in lanes lr3=0..3) [r8] ----
        const float bbv = (L == 2 && t >= 80) ? bbd : bbe;
        float z[4], t0[4];
        #pragma unroll
        for (int j = 0; j < 4; j++) {
            z[j] = accA[j] + accB[j] + bbv + zx[j];
            t0[j] = (lr3 == 2) ? fast_tanh(z[j]) : fast_sigmoid(z[j]);
        }
        float av[4], cn[4], tc[4], hn[4];
        #pragma unroll
        for (int j = 0; j < 4; j++) {
            float x2 = __shfl_xor(t0[j], 2);     // lane0 <- tanh(g)
            av[j] = t0[j] * x2;                  // lane0: sig(i)*tanh(g)
        }
        #pragma unroll
        for (int j = 0; j < 4; j++) {
            float x1 = __shfl_xor(av[j], 1);     // lane1 <- a
            cn[j] = t0[j] * cc[j] + x1;          // lane1: sig(f)*c + a
            cc[j] = cn[j];
            tc[j] = fast_tanh(cn[j]);
        }
        #pragma unroll
        for (int j = 0; j < 4; j++) {
            float x2b = __shfl_xor(tc[j], 2);    // lane3 <- tanh(c')
            hn[j] = t0[j] * x2b;                 // lane3: sig(o)*tanh(c')
        }

        // ---- publish h (lanes lr3==3), packed (hi|lo) u32 ----
        if (lr3 == 3) {
            unsigned* wb = myb + (size_t)(t & (DQ-1))*16384;
            #pragma unroll
            for (int j = 0; j < 4; j++) {
                int b = mh*16 + kg*4 + j;
                float v = hn[j];
                if (L == 3 && t >= 80)
                    dec3h[(size_t)(t-80)*(BSZ*NHID) + b*512 + hcol] = (__bf16)v;
                __hip_atomic_store(&wb[b*512 + hcol], pack_hilo(v),
                                   __ATOMIC_RELAXED, __HIP_MEMORY_SCOPE_AGENT);
            }
        }

        // ---- step-complete: release + single RMW ----
        __syncthreads();
        if (tid == 0) {
            __builtin_amdgcn_fence(__ATOMIC_RELEASE, "agent");
            __hip_atomic_fetch_add(&cnt[L*32], 1u, __ATOMIC_RELAXED,
                                   __HIP_MEMORY_SCOPE_AGENT);
        }
    }
}

// ---------------------------------------------------------------------------
// bias2[j] = l2_b0[j] + sum_h (W_emb[h*NTOK+0] + b_emb[h]) * Wih0[j*1024+h]
// ---------------------------------------------------------------------------
__global__ __launch_bounds__(256) void bias2_kernel(
    const float* __restrict__ W_emb,
    const float* __restrict__ b_emb,
    const float* __restrict__ Wih0,
    const float* __restrict__ b0,
    float* __restrict__ bias2)
{
    __shared__ float bos[NHID];
    const int tid = threadIdx.x;
    for (int i = tid; i < NHID; i += 256)
        bos[i] = W_emb[(size_t)i * NTOK] + b_emb[i];
    __syncthreads();
    int j = blockIdx.x * 256 + tid;
    float acc = b0[j];
    for (int k = 0; k < NHID; k++)
        acc += bos[k] * Wih0[(size_t)j * 1024 + k];
    bias2[j] = acc;
}

// ---------------------------------------------------------------------------
// In-place log_softmax over rows of 50257 (online max+sum).
// ---------------------------------------------------------------------------
__global__ __launch_bounds__(256) void logsoftmax_kernel(float* __restrict__ logits)
{
    const size_t row = blockIdx.x;
    float* p = logits + row * (size_t)NTOK;
    const int tid = threadIdx.x;

    float m = -1e30f, s = 0.f;
    for (int i = tid; i < NTOK; i += 256) {
        float x = p[i];
        float mn = fmaxf(m, x);
        s = s * __expf(m - mn) + __expf(x - mn);
        m = mn;
    }
    #pragma unroll
    for (int off = 32; off > 0; off >>= 1) {
        float mo = __shfl_down(m, off);
        float so = __shfl_down(s, off);
        float mn = fmaxf(m, mo);
        s = s * __expf(m - mn) + so * __expf(mo - mn);
        m = mn;
    }
    __shared__ float sm[4], ss[4];
    if ((tid & 63) == 0) { sm[tid >> 6] = m; ss[tid >> 6] = s; }
    __syncthreads();
    float M4 = fmaxf(fmaxf(sm[0], sm[1]), fmaxf(sm[2], sm[3]));
    float S  = ss[0] * __expf(sm[0] - M4) + ss[1] * __expf(sm[1] - M4)
             + ss[2] * __expf(sm[2] - M4) + ss[3] * __expf(sm[3] - M4);
    float lse = M4 + logf(S);
    for (int i = tid; i < NTOK; i += 256) p[i] = p[i] - lse;
}

// ---------------------------------------------------------------------------
extern "C" void kernel_launch(void* const* d_in, const int* in_sizes, int n_in,
                              void* d_out, int out_size, void* d_ws, size_t ws_size,
                              hipStream_t stream)
{
    const float* inp     = (const float*)d_in[0];
    const float* hid1_h  = (const float*)d_in[1];
    const float* hid1_c  = (const float*)d_in[2];
    const float* hid2_h  = (const float*)d_in[3];
    const float* hid2_c  = (const float*)d_in[4];
    const float* l1_Wih0 = (const float*)d_in[5];
    const float* l1_Whh0 = (const float*)d_in[6];
    const float* l1_b0   = (const float*)d_in[7];
    const float* l1_Wih1 = (const float*)d_in[8];
    const float* l1_Whh1 = (const float*)d_in[9];
    const float* l1_b1   = (const float*)d_in[10];
    const float* l2_Wih0 = (const float*)d_in[11];
    const float* l2_Whh0 = (const float*)d_in[12];
    const float* l2_b0   = (const float*)d_in[13];
    const float* l2_Wih1 = (const float*)d_in[14];
    const float* l2_Whh1 = (const float*)d_in[15];
    const float* l2_b1   = (const float*)d_in[16];
    const float* W_out   = (const float*)d_in[17];
    const float* b_out   = (const float*)d_in[18];
    const float* W_emb   = (const float*)d_in[19];
    const float* b_emb   = (const float*)d_in[20];

    float* out = (float*)d_out;   // [40,32,50257]
    float* ws  = (float*)d_ws;

    // workspace layout (floats)
    float* Zx    = ws;                                  // [2560,2048]
    float* bias2 = ws + 5242880;                        // [2048]
    __bf16* dec3h = (__bf16*)(ws + 5244928);            // [1280][512] bf16
    unsigned* hbuf = (unsigned*)(ws + 5572608);         // [4][DQ][16384] u32
    unsigned* cnt  = (unsigned*)(ws + 5703680);         // 4 x (stride 32 u32)

    (void)hipMemsetAsync(cnt, 0, 512, stream);

    // encoder lstm1 layer0 input projection (only precomputed Zx)
    {
        dim3 grid((G4 + 127) / 128, (T_ENC * BSZ) / 128);
        gemm_hilo<<<grid, dim3(256), 0, stream>>>(
            inp, NINP, l1_Wih0, NINP, nullptr, Zx, G4, G4, NINP);
    }
    bias2_kernel<<<8, 256, 0, stream>>>(W_emb, b_emb, l2_Wih0, l2_b0, bias2);

    // fused pipelined scan: all 4 layers, atomic-counter dataflow sync
    fused_scan<<<256, 256, 0, stream>>>(
        Zx,
        l1_Whh0, l1_b0,
        l1_Wih1, l1_Whh1, l1_b1,
        l2_Wih0 + 512, l2_Whh0, l2_b0, bias2,
        l2_Wih1, l2_Whh1, l2_b1,
        hid1_h, hid1_c, hid2_h, hid2_c,
        dec3h, hbuf, cnt);

    // vocab projection + log_softmax
    gemm_vocab<<<(NTOK + 127) / 128, dim3(256), 0, stream>>>(
        dec3h, W_out, b_out, out);
    logsoftmax_kernel<<<1280, dim3(256), 0, stream>>>(out);
}

// Round 12
// 1914.315 us; speedup vs baseline: 1.0766x; 1.0766x over previous
//
#include <hip/hip_runtime.h>
#include <hip/hip_bf16.h>
#include <cstddef>

// Problem constants (fixed by the harness shapes)
#define NINP 4096
#define NHID 512
#define G4   2048   // 4*NHID
#define NTOK 50257
#define BSZ  32
#define T_ENC 80
#define T_DEC 40

typedef __attribute__((ext_vector_type(4))) float  f32x4;
typedef __attribute__((ext_vector_type(4))) __bf16 bf16x4;
typedef __attribute__((ext_vector_type(8))) __bf16 bf16x8;

// ---------------------------------------------------------------------------
// XOR-swizzled byte offsets (row-major bf16 tiles, 16B-slot XOR row&7)
// ---------------------------------------------------------------------------
__device__ __forceinline__ int sw_off(int r, int k) {   // [rows][64] bf16
    return r * 128 + ((((k >> 3) ^ (r & 7)) << 4) | ((k & 7) << 1));
}
__device__ __forceinline__ int swA(int r, int k) {      // [rows][128] bf16
    return r * 256 + ((((k >> 3) ^ (r & 7)) << 4) | ((k & 7) << 1));
}
__device__ __forceinline__ int sw512(int r, int k) {    // [rows][512] bf16
    return r * 1024 + ((((k >> 3) ^ (r & 7)) << 4) | ((k & 7) << 1));
}

__device__ __forceinline__ bf16x4 hi4(const float4& v) {
    bf16x4 h; h[0] = (__bf16)v.x; h[1] = (__bf16)v.y;
    h[2] = (__bf16)v.z; h[3] = (__bf16)v.w; return h;
}

__device__ __forceinline__ void split8(const float4& a, const float4& b,
                                       bf16x8& h, bf16x8& l) {
    float x[8] = {a.x, a.y, a.z, a.w, b.x, b.y, b.z, b.w};
    #pragma unroll
    for (int i = 0; i < 8; i++) {
        __bf16 hb = (__bf16)x[i];
        h[i] = hb; l[i] = (__bf16)(x[i] - (float)hb);
    }
}

__device__ __forceinline__ bf16x8 to_bf16x8(const float4& a, const float4& b) {
    bf16x8 r;
    r[0]=(__bf16)a.x; r[1]=(__bf16)a.y; r[2]=(__bf16)a.z; r[3]=(__bf16)a.w;
    r[4]=(__bf16)b.x; r[5]=(__bf16)b.y; r[6]=(__bf16)b.z; r[7]=(__bf16)b.w;
    return r;
}

__device__ __forceinline__ void unpack8(const uint4& a, const uint4& b,
                                        bf16x8& h, bf16x8& l) {
    unsigned u[8] = {a.x, a.y, a.z, a.w, b.x, b.y, b.z, b.w};
    union { unsigned short s; __bf16 v; } t;
    #pragma unroll
    for (int i = 0; i < 8; i++) {
        t.s = (unsigned short)(u[i] & 0xffff); h[i] = t.v;
        t.s = (unsigned short)(u[i] >> 16);    l[i] = t.v;
    }
}
__device__ __forceinline__ bf16x8 unpack_hi8(const uint4& a, const uint4& b) {
    unsigned u[8] = {a.x, a.y, a.z, a.w, b.x, b.y, b.z, b.w};
    union { unsigned short s; __bf16 v; } t;
    bf16x8 h;
    #pragma unroll
    for (int i = 0; i < 8; i++) { t.s = (unsigned short)(u[i] & 0xffff); h[i] = t.v; }
    return h;
}

__device__ __forceinline__ unsigned pack_hilo(float x) {
    __bf16 hb = (__bf16)x;
    float hf = (float)hb;
    __bf16 lb = (__bf16)(x - hf);
    union { __bf16 b; unsigned short s; } ch, cl;
    ch.b = hb; cl.b = lb;
    return (unsigned)ch.s | ((unsigned)cl.s << 16);
}

__device__ __forceinline__ float fast_sigmoid(float x) {
    return 1.f / (1.f + __expf(-x));
}
__device__ __forceinline__ float fast_tanh(float x) {
    return 1.f - 2.f / (__expf(2.f * x) + 1.f);
}

// ---------------------------------------------------------------------------
// 1-pass bf16 GEMM (A hi, B hi): input projection + (verified round 5).
// Z[m][n] = bias[n] + sum_k A[m][k]*B[n][k]; M = gridDim.y*128.
// ---------------------------------------------------------------------------
__global__ __launch_bounds__(256) void gemm_ahi(
    const float* __restrict__ A, int lda,
    const float* __restrict__ B, int ldb,
    const float* __restrict__ bias,
    float* __restrict__ Z, int ldz,
    int N, int K)
{
    __shared__ __align__(16) char lds[32768];
    const int tid  = threadIdx.x;
    const int bm   = blockIdx.y * 128;
    const int bn   = blockIdx.x * 128;
    const int wave = tid >> 6;
    const int lane = tid & 63;
    const int wm   = (wave >> 1) * 64;
    const int wn   = (wave & 1) * 64;
    const int lr   = lane & 15;
    const int kg   = lane >> 4;

    const int rr = tid >> 4;
    const int kk = (tid & 15) * 4;

    f32x4 acc[4][4] = {};

    for (int k0 = 0; k0 < K; k0 += 64) {
        float4 av[8], bv[8];
        #pragma unroll
        for (int i = 0; i < 8; i++) {
            int r = i * 16 + rr;
            av[i] = *(const float4*)&A[(size_t)(bm + r) * lda + k0 + kk];
            int rb = bn + r;
            if (rb < N)
                bv[i] = *(const float4*)&B[(size_t)rb * ldb + k0 + kk];
            else
                bv[i] = make_float4(0.f, 0.f, 0.f, 0.f);
        }
        __syncthreads();
        #pragma unroll
        for (int i = 0; i < 8; i++) {
            int r = i * 16 + rr;
            int off = sw_off(r, kk);
            *(bf16x4*)(lds + off)         = hi4(av[i]);
            *(bf16x4*)(lds + 16384 + off) = hi4(bv[i]);
        }
        __syncthreads();
        #pragma unroll
        for (int ks = 0; ks < 2; ks++) {
            bf16x8 ah[4], bh[4];
            const int kbase = ks * 32 + kg * 8;
            #pragma unroll
            for (int f = 0; f < 4; f++) {
                ah[f] = *(const bf16x8*)(lds + sw_off(wm + f * 16 + lr, kbase));
                bh[f] = *(const bf16x8*)(lds + 16384 + sw_off(wn + f * 16 + lr, kbase));
            }
            #pragma unroll
            for (int fm = 0; fm < 4; fm++)
                #pragma unroll
                for (int fn = 0; fn < 4; fn++)
                    acc[fm][fn] = __builtin_amdgcn_mfma_f32_16x16x32_bf16(
                        ah[fm], bh[fn], acc[fm][fn], 0, 0, 0);
        }
        __syncthreads();
    }

    #pragma unroll
    for (int fn = 0; fn < 4; fn++) {
        int col = bn + wn + fn * 16 + lr;
        if (col < N) {
            float bb = bias ? bias[col] : 0.f;
            #pragma unroll
            for (int fm = 0; fm < 4; fm++) {
                #pragma unroll
                for (int j = 0; j < 4; j++) {
                    int row = bm + wm + fm * 16 + kg * 4 + j;
                    Z[(size_t)row * ldz + col] = acc[fm][fn][j] + bb;
                }
            }
        }
    }
}

// ---------------------------------------------------------------------------
// Vocab projection: Z[1280][50257] = dec3h[1280][512](bf16) @ W_out^T + b_out.
// W_out panel staged once per block. (verified rounds 7-11)
// ---------------------------------------------------------------------------
__global__ __launch_bounds__(256, 1) void gemm_vocab(
    const __bf16* __restrict__ Ah,    // [1280][512] bf16
    const float* __restrict__ B,      // [50257][512] fp32
    const float* __restrict__ bias,   // [50257]
    float* __restrict__ Z)            // [1280][50257]
{
    __shared__ __align__(16) char lds[163840];  // B panel 128K | A tile 32K
    char* ldsB = lds;
    char* ldsA = lds + 131072;

    const int tid  = threadIdx.x;
    const int bn   = blockIdx.x * 128;
    const int wave = tid >> 6;
    const int lane = tid & 63;
    const int wm   = (wave >> 1) * 64;
    const int wn   = (wave & 1) * 64;
    const int lr   = lane & 15;
    const int kg   = lane >> 4;

    // ---- stage B panel once (fp32 -> bf16, swizzled) ----
    #pragma unroll 4
    for (int jj = 0; jj < 32; jj++) {
        int e = tid + jj * 256;           // 0..8191
        int row = e >> 6;                 // 0..127
        int k = (e & 63) * 8;             // 0..504
        int gr = bn + row;
        float4 v0, v1;
        if (gr < NTOK) {
            v0 = *(const float4*)&B[(size_t)gr * 512 + k];
            v1 = *(const float4*)&B[(size_t)gr * 512 + k + 4];
        } else {
            v0 = make_float4(0.f,0.f,0.f,0.f); v1 = v0;
        }
        *(bf16x8*)(ldsB + sw512(row, k)) = to_bf16x8(v0, v1);
    }

    float bb[4];
    #pragma unroll
    for (int fn = 0; fn < 4; fn++) {
        int col = bn + wn + fn * 16 + lr;
        bb[fn] = (col < NTOK) ? bias[col] : 0.f;
    }
    __syncthreads();

    for (int mt = 0; mt < 10; mt++) {
        f32x4 acc[4][4] = {};
        for (int k0 = 0; k0 < 4; k0++) {
            __syncthreads();   // WAR on A tile
            #pragma unroll
            for (int jj = 0; jj < 8; jj++) {
                int e = tid + jj * 256;       // 0..2047
                int row = e >> 4;             // 0..127
                int k = (e & 15) * 8;         // 0..120
                uint4 v = *(const uint4*)&Ah[(size_t)(mt * 128 + row) * 512 + k0 * 128 + k];
                *(uint4*)(ldsA + swA(row, k)) = v;
            }
            __syncthreads();
            #pragma unroll
            for (int ks = 0; ks < 4; ks++) {
                bf16x8 ah[4], bh[4];
                const int ka = ks * 32 + kg * 8;
                #pragma unroll
                for (int f = 0; f < 4; f++) {
                    ah[f] = *(const bf16x8*)(ldsA + swA(wm + f * 16 + lr, ka));
                    bh[f] = *(const bf16x8*)(ldsB + sw512(wn + f * 16 + lr, k0 * 128 + ka));
                }
                #pragma unroll
                for (int fm = 0; fm < 4; fm++)
                    #pragma unroll
                    for (int fn = 0; fn < 4; fn++)
                        acc[fm][fn] = __builtin_amdgcn_mfma_f32_16x16x32_bf16(
                            ah[fm], bh[fn], acc[fm][fn], 0, 0, 0);
            }
        }
        #pragma unroll
        for (int fn = 0; fn < 4; fn++) {
            int col = bn + wn + fn * 16 + lr;
            if (col < NTOK) {
                #pragma unroll
                for (int fm = 0; fm < 4; fm++) {
                    #pragma unroll
                    for (int j = 0; j < 4; j++) {
                        int row = mt * 128 + wm + fm * 16 + kg * 4 + j;
                        Z[(size_t)row * NTOK + col] = acc[fm][fn][j] + bb[fn];
                    }
                }
            }
        }
    }
}

// ---------------------------------------------------------------------------
// Grid barrier (256 blocks, 1/CU co-resident): two-hop, single gen broadcast.
// r5/r9-proven; change: leader gather spins hard (no s_sleep) to cut
// detection latency on the critical hop.
// ---------------------------------------------------------------------------
__device__ __forceinline__ void grid_barrier(unsigned* flags, unsigned* gen,
                                             unsigned target)
{
    __syncthreads();
    if (threadIdx.x == 0) {
        __builtin_amdgcn_fence(__ATOMIC_RELEASE, "agent");
        __hip_atomic_store(&flags[blockIdx.x], target, __ATOMIC_RELAXED,
                           __HIP_MEMORY_SCOPE_AGENT);
    }
    if (blockIdx.x == 0) {
        while (__hip_atomic_load(&flags[threadIdx.x], __ATOMIC_RELAXED,
                                 __HIP_MEMORY_SCOPE_AGENT) < target)
            ;   // hard spin — leader only
        __syncthreads();
        if (threadIdx.x == 0)
            __hip_atomic_store(gen, target, __ATOMIC_RELAXED,
                               __HIP_MEMORY_SCOPE_AGENT);
    }
    if (threadIdx.x == 0) {
        while (__hip_atomic_load(gen, __ATOMIC_RELAXED,
                                 __HIP_MEMORY_SCOPE_AGENT) < target)
            __builtin_amdgcn_s_sleep(1);
        __builtin_amdgcn_fence(__ATOMIC_ACQUIRE, "agent");
    }
    __syncthreads();
}

// ---------------------------------------------------------------------------
// Fused 4-layer pipelined LSTM scan — round-9 structure (best measured:
// 1232 us), plus: Zx for the NEXT step prefetched into registers right after
// z-finalize (loads fly during gate math + barrier instead of serializing at
// step start; Zx is static data, safe to read at any time).
// 256 blocks: layer L = blockIdx>>6 (64 col-blocks each). Global step tt:
// layer L processes myt = tt-L (0..119). h broadcast via packed (hi|lo) u32
// hbuf, slot = myt&1 per layer. LDS: A_hi 0..32K, A_lo 32K..64K (a_x
// aliases), Whh_hi 64K..96K, Wih_hi 96K..128K.
// ---------------------------------------------------------------------------
__global__ __launch_bounds__(256, 1) void fused_scan(
    const float* __restrict__ Zx,
    const float* __restrict__ Whh_0, const float* __restrict__ bias_0,
    const float* __restrict__ Wih_1, const float* __restrict__ Whh_1,
    const float* __restrict__ bias_1,
    const float* __restrict__ Wih_2, const float* __restrict__ Whh_2,
    const float* __restrict__ bias_2e, const float* __restrict__ bias_2d,
    const float* __restrict__ Wih_3, const float* __restrict__ Whh_3,
    const float* __restrict__ bias_3,
    const float* __restrict__ hid1_h, const float* __restrict__ hid1_c,
    const float* __restrict__ hid2_h, const float* __restrict__ hid2_c,
    __bf16* __restrict__ dec3h,
    unsigned* hbuf, unsigned* flags, unsigned* gen)
{
    __shared__ __align__(16) char lds[131072];
    float* a_x = (float*)(lds + 32768);   // aliases A_lo (restaged each step)

    const int tid  = threadIdx.x;
    const int L    = blockIdx.x >> 6;
    const int bidc = blockIdx.x & 63;
    const int wave = tid >> 6;
    const int lane = tid & 63;
    const int mh   = wave >> 1;
    const int nh   = wave & 1;
    const int lr   = lane & 15;
    const int kg   = lane >> 4;
    const int jcbase = bidc * 8;
    const int bq = tid >> 3;     // staging row 0..31
    const int aq = tid & 7;      // staging k-lane

    const float* Whh = (L==0)?Whh_0:(L==1)?Whh_1:(L==2)?Whh_2:Whh_3;
    const float* Wih = (L==1)?Wih_1:(L==2)?Wih_2:(L==3)?Wih_3:nullptr;
    const int ld_ih  = (L==2)?1024:512;
    const float* be  = (L==0)?bias_0:(L==1)?bias_1:(L==2)?bias_2e:bias_3;
    const float* bd  = (L==2)?bias_2d:be;
    const float* h0  = ((L<2)?hid1_h:hid2_h) + (L&1)*16384;
    const float* c0  = ((L<2)?hid1_c:hid2_c) + (L&1)*16384;
    unsigned* myb       = hbuf + L*32768;
    const unsigned* xsb = hbuf + (L>0 ? (L-1)*32768 : 0);

    // ---- stage weights hi-only, once ----
    {
        int gate = (bq<8)?0:(bq<16)?2:(bq<24)?1:3;   // rows: i,g,f,o
        int row  = gate*512 + jcbase + (bq&7);
        const float* wr = Whh + (size_t)row * 512;
        #pragma unroll
        for (int jj = 0; jj < 8; jj++) {
            int k = aq*8 + jj*64;
            *(bf16x8*)(lds + 65536 + sw512(bq, k)) =
                to_bf16x8(*(const float4*)(wr+k), *(const float4*)(wr+k+4));
        }
        if (Wih) {
            const float* wr2 = Wih + (size_t)row * ld_ih;
            #pragma unroll
            for (int jj = 0; jj < 8; jj++) {
                int k = aq*8 + jj*64;
                *(bf16x8*)(lds + 98304 + sw512(bq, k)) =
                    to_bf16x8(*(const float4*)(wr2+k), *(const float4*)(wr2+k+4));
            }
        }
    }

    // lane's output-column mapping
    const int n_col = nh*16 + lr;
    const int gate  = (n_col<8)?0:(n_col<16)?2:(n_col<24)?1:3;
    const int col2048 = gate*512 + jcbase + (n_col & 7);
    const float bbe = be[col2048];
    const float bbd = bd[col2048];

    // c state: nh==1, lr<8 lanes, 4 batches each
    float cc[4] = {0.f, 0.f, 0.f, 0.f};
    if (nh == 1 && lr < 8) {
        #pragma unroll
        for (int j = 0; j < 4; j++)
            cc[j] = c0[(mh*16 + kg*4 + j)*512 + jcbase + lr];
    }

    // ---- Zx prefetch for the first step (L0 only) ----
    float zxr[4] = {0.f, 0.f, 0.f, 0.f};
    if (L == 0) {
        #pragma unroll
        for (int j = 0; j < 4; j++)
            zxr[j] = Zx[(size_t)(mh*16 + kg*4 + j)*G4 + col2048];
    }
    __syncthreads();

    const int rowA = mh*16 + lr;
    const int rowB = nh*16 + lr;

    for (int tt = 0; tt < 123; ++tt) {
        const int myt = tt - L;
        if (myt >= 0 && myt < 120) {
            // ---- hoist x loads (L>=1) ----
            uint4 xr[8][2];
            if (L > 0) {
                const unsigned* xs = xsb + (size_t)(myt & 1)*16384 + bq*512;
                #pragma unroll
                for (int jj = 0; jj < 8; jj++) {
                    int k = aq*8 + jj*64;
                    xr[jj][0] = *(const uint4*)(xs + k);
                    xr[jj][1] = *(const uint4*)(xs + k + 4);
                }
            }
            // ---- stage h (hi/lo) ----
            if (myt == 0) {
                const float* hr = h0 + bq*512;
                #pragma unroll
                for (int jj = 0; jj < 8; jj++) {
                    int k = aq*8 + jj*64;
                    bf16x8 H, Lo;
                    split8(*(const float4*)(hr+k), *(const float4*)(hr+k+4), H, Lo);
                    int off = sw512(bq, k);
                    *(bf16x8*)(lds + off)         = H;
                    *(bf16x8*)(lds + 32768 + off) = Lo;
                }
            } else {
                const unsigned* hs = myb + (size_t)((myt-1) & 1)*16384 + bq*512;
                #pragma unroll
                for (int jj = 0; jj < 8; jj++) {
                    int k = aq*8 + jj*64;
                    bf16x8 H, Lo;
                    unpack8(*(const uint4*)(hs+k), *(const uint4*)(hs+k+4), H, Lo);
                    int off = sw512(bq, k);
                    *(bf16x8*)(lds + off)         = H;
                    *(bf16x8*)(lds + 32768 + off) = Lo;
                }
            }
            __syncthreads();

            // ---- phase 1: h @ Whh^T (2-pass, split accumulators) ----
            f32x4 accA = {0.f,0.f,0.f,0.f}, accB = {0.f,0.f,0.f,0.f};
            #pragma unroll
            for (int ks = 0; ks < 16; ++ks) {
                int k = ks*32 + kg*8;
                int offA = sw512(rowA, k);
                int offB = sw512(rowB, k);
                bf16x8 ah = *(const bf16x8*)(lds + offA);
                bf16x8 al = *(const bf16x8*)(lds + 32768 + offA);
                bf16x8 bh = *(const bf16x8*)(lds + 65536 + offB);
                accA = __builtin_amdgcn_mfma_f32_16x16x32_bf16(ah, bh, accA, 0,0,0);
                accB = __builtin_amdgcn_mfma_f32_16x16x32_bf16(al, bh, accB, 0,0,0);
            }
            __syncthreads();

            // ---- phase 2: x @ Wih^T (hi only) ----
            if (L > 0) {
                #pragma unroll
                for (int jj = 0; jj < 8; jj++) {
                    int k = aq*8 + jj*64;
                    *(bf16x8*)(lds + sw512(bq, k)) = unpack_hi8(xr[jj][0], xr[jj][1]);
                }
                __syncthreads();
                #pragma unroll
                for (int ks = 0; ks < 16; ++ks) {
                    int k = ks*32 + kg*8;
                    bf16x8 ax = *(const bf16x8*)(lds + sw512(rowA, k));
                    bf16x8 bi = *(const bf16x8*)(lds + 98304 + sw512(rowB, k));
                    accA = __builtin_amdgcn_mfma_f32_16x16x32_bf16(ax, bi, accA, 0,0,0);
                }
            }

            // ---- finalize z (uses prefetched zxr), then prefetch next Zx ----
            const float bbv = (L == 2 && myt >= 80) ? bbd : bbe;
            float z[4];
            #pragma unroll
            for (int j = 0; j < 4; j++)
                z[j] = accA[j] + accB[j] + bbv
                     + ((L == 0 && myt < 80) ? zxr[j] : 0.f);

            {
                int mytn = myt + 1;
                if (L == 0 && mytn < 80) {
                    #pragma unroll
                    for (int j = 0; j < 4; j++)
                        zxr[j] = Zx[(size_t)mytn*(BSZ*G4)
                                    + (mh*16+kg*4+j)*G4 + col2048];
                }
            }

            if (nh == 0) {
                // lr<8: z=i ; lr>=8: z=g -> a = sig(i)*tanh(g)
                float zo[4];
                #pragma unroll
                for (int j = 0; j < 4; j++) zo[j] = __shfl_xor(z[j], 8);
                if (lr < 8) {
                    #pragma unroll
                    for (int j = 0; j < 4; j++)
                        a_x[(mh*16 + kg*4 + j)*8 + lr] =
                            fast_sigmoid(z[j]) * fast_tanh(zo[j]);
                }
            }
            __syncthreads();

            if (nh == 1) {
                // lr<8: z=f ; lr>=8: z=o
                float cnew[4] = {0.f,0.f,0.f,0.f};
                if (lr < 8) {
                    #pragma unroll
                    for (int j = 0; j < 4; j++) {
                        float av = a_x[(mh*16 + kg*4 + j)*8 + lr];
                        cnew[j] = fast_sigmoid(z[j]) * cc[j] + av;
                        cc[j] = cnew[j];
                    }
                }
                float cfrom[4];
                #pragma unroll
                for (int j = 0; j < 4; j++) cfrom[j] = __shfl_xor(cnew[j], 8);
                if (lr >= 8) {
                    #pragma unroll
                    for (int j = 0; j < 4; j++) {
                        float hn = fast_sigmoid(z[j]) * fast_tanh(cfrom[j]);
                        int b = mh*16 + kg*4 + j;
                        int hcol = jcbase + (lr - 8);
                        if (L == 3 && myt >= 80)
                            dec3h[(size_t)(myt-80)*(BSZ*NHID) + b*512 + hcol] =
                                (__bf16)hn;
                        __hip_atomic_store(&myb[(size_t)(myt & 1)*16384 + b*512 + hcol],
                                           pack_hilo(hn), __ATOMIC_RELAXED,
                                           __HIP_MEMORY_SCOPE_AGENT);
                    }
                }
            }
        }
        grid_barrier(flags, gen, (unsigned)tt + 1u);
    }
}

// ---------------------------------------------------------------------------
// bias2[j] = l2_b0[j] + sum_h (W_emb[h*NTOK+0] + b_emb[h]) * Wih0[j*1024+h]
// ---------------------------------------------------------------------------
__global__ __launch_bounds__(256) void bias2_kernel(
    const float* __restrict__ W_emb,
    const float* __restrict__ b_emb,
    const float* __restrict__ Wih0,
    const float* __restrict__ b0,
    float* __restrict__ bias2)
{
    __shared__ float bos[NHID];
    const int tid = threadIdx.x;
    for (int i = tid; i < NHID; i += 256)
        bos[i] = W_emb[(size_t)i * NTOK] + b_emb[i];
    __syncthreads();
    int j = blockIdx.x * 256 + tid;
    float acc = b0[j];
    for (int k = 0; k < NHID; k++)
        acc += bos[k] * Wih0[(size_t)j * 1024 + k];
    bias2[j] = acc;
}

// ---------------------------------------------------------------------------
// In-place log_softmax over rows of 50257 (online max+sum).
// ---------------------------------------------------------------------------
__global__ __launch_bounds__(256) void logsoftmax_kernel(float* __restrict__ logits)
{
    const size_t row = blockIdx.x;
    float* p = logits + row * (size_t)NTOK;
    const int tid = threadIdx.x;

    float m = -1e30f, s = 0.f;
    for (int i = tid; i < NTOK; i += 256) {
        float x = p[i];
        float mn = fmaxf(m, x);
        s = s * __expf(m - mn) + __expf(x - mn);
        m = mn;
    }
    #pragma unroll
    for (int off = 32; off > 0; off >>= 1) {
        float mo = __shfl_down(m, off);
        float so = __shfl_down(s, off);
        float mn = fmaxf(m, mo);
        s = s * __expf(m - mn) + so * __expf(mo - mn);
        m = mn;
    }
    __shared__ float sm[4], ss[4];
    if ((tid & 63) == 0) { sm[tid >> 6] = m; ss[tid >> 6] = s; }
    __syncthreads();
    float M4 = fmaxf(fmaxf(sm[0], sm[1]), fmaxf(sm[2], sm[3]));
    float S  = ss[0] * __expf(sm[0] - M4) + ss[1] * __expf(sm[1] - M4)
             + ss[2] * __expf(sm[2] - M4) + ss[3] * __expf(sm[3] - M4);
    float lse = M4 + logf(S);
    for (int i = tid; i < NTOK; i += 256) p[i] = p[i] - lse;
}

// ---------------------------------------------------------------------------
extern "C" void kernel_launch(void* const* d_in, const int* in_sizes, int n_in,
                              void* d_out, int out_size, void* d_ws, size_t ws_size,
                              hipStream_t stream)
{
    const float* inp     = (const float*)d_in[0];
    const float* hid1_h  = (const float*)d_in[1];
    const float* hid1_c  = (const float*)d_in[2];
    const float* hid2_h  = (const float*)d_in[3];
    const float* hid2_c  = (const float*)d_in[4];
    const float* l1_Wih0 = (const float*)d_in[5];
    const float* l1_Whh0 = (const float*)d_in[6];
    const float* l1_b0   = (const float*)d_in[7];
    const float* l1_Wih1 = (const float*)d_in[8];
    const float* l1_Whh1 = (const float*)d_in[9];
    const float* l1_b1   = (const float*)d_in[10];
    const float* l2_Wih0 = (const float*)d_in[11];
    const float* l2_Whh0 = (const float*)d_in[12];
    const float* l2_b0   = (const float*)d_in[13];
    const float* l2_Wih1 = (const float*)d_in[14];
    const float* l2_Whh1 = (const float*)d_in[15];
    const float* l2_b1   = (const float*)d_in[16];
    const float* W_out   = (const float*)d_in[17];
    const float* b_out   = (const float*)d_in[18];
    const float* W_emb   = (const float*)d_in[19];
    const float* b_emb   = (const float*)d_in[20];

    float* out = (float*)d_out;   // [40,32,50257]
    float* ws  = (float*)d_ws;

    // workspace layout (floats)
    float* Zx    = ws;                                  // [2560,2048]
    float* bias2 = ws + 5242880;                        // [2048]
    __bf16* dec3h = (__bf16*)(ws + 5244928);            // [1280][512] bf16
    unsigned* hbuf  = (unsigned*)(ws + 5572608);        // [4][2][16384] u32
    unsigned* flags = (unsigned*)(ws + 5703680);        // 256 + gen
    unsigned* gen   = flags + 256;

    (void)hipMemsetAsync(flags, 0, 1028, stream);

    // encoder lstm1 layer0 input projection (1-pass A-hi, B-hi)
    {
        dim3 grid((G4 + 127) / 128, (T_ENC * BSZ) / 128);
        gemm_ahi<<<grid, dim3(256), 0, stream>>>(
            inp, NINP, l1_Wih0, NINP, nullptr, Zx, G4, G4, NINP);
    }
    bias2_kernel<<<8, 256, 0, stream>>>(W_emb, b_emb, l2_Wih0, l2_b0, bias2);

    // fused pipelined scan: all 4 layers, encoder + decoder, one launch
    fused_scan<<<256, 256, 0, stream>>>(
        Zx,
        l1_Whh0, l1_b0,
        l1_Wih1, l1_Whh1, l1_b1,
        l2_Wih0 + 512, l2_Whh0, l2_b0, bias2,
        l2_Wih1, l2_Whh1, l2_b1,
        hid1_h, hid1_c, hid2_h, hid2_c,
        dec3h, hbuf, flags, gen);

    // vocab projection + log_softmax
    gemm_vocab<<<(NTOK + 127) / 128, dim3(256), 0, stream>>>(
        dec3h, W_out, b_out, out);
    logsoftmax_kernel<<<1280, dim3(256), 0, stream>>>(out);
}

// Round 13
// 1814.548 us; speedup vs baseline: 1.1358x; 1.0550x over previous
//
#include <hip/hip_runtime.h>
#include <hip/hip_bf16.h>
#include <cstddef>

// Problem constants (fixed by the harness shapes)
#define NINP 4096
#define NHID 512
#define G4   2048   // 4*NHID
#define NTOK 50257
#define BSZ  32
#define T_ENC 80
#define T_DEC 40

typedef __attribute__((ext_vector_type(4))) float  f32x4;
typedef __attribute__((ext_vector_type(4))) __bf16 bf16x4;
typedef __attribute__((ext_vector_type(8))) __bf16 bf16x8;

// ---------------------------------------------------------------------------
// XOR-swizzled byte offsets (row-major bf16 tiles, 16B-slot XOR row&7)
// ---------------------------------------------------------------------------
__device__ __forceinline__ int sw_off(int r, int k) {   // [rows][64] bf16
    return r * 128 + ((((k >> 3) ^ (r & 7)) << 4) | ((k & 7) << 1));
}
__device__ __forceinline__ int sw512(int r, int k) {    // [rows][512] bf16
    return r * 1024 + ((((k >> 3) ^ (r & 7)) << 4) | ((k & 7) << 1));
}

__device__ __forceinline__ bf16x4 hi4(const float4& v) {
    bf16x4 h; h[0] = (__bf16)v.x; h[1] = (__bf16)v.y;
    h[2] = (__bf16)v.z; h[3] = (__bf16)v.w; return h;
}

__device__ __forceinline__ void split8(const float4& a, const float4& b,
                                       bf16x8& h, bf16x8& l) {
    float x[8] = {a.x, a.y, a.z, a.w, b.x, b.y, b.z, b.w};
    #pragma unroll
    for (int i = 0; i < 8; i++) {
        __bf16 hb = (__bf16)x[i];
        h[i] = hb; l[i] = (__bf16)(x[i] - (float)hb);
    }
}

__device__ __forceinline__ bf16x8 to_bf16x8(const float4& a, const float4& b) {
    bf16x8 r;
    r[0]=(__bf16)a.x; r[1]=(__bf16)a.y; r[2]=(__bf16)a.z; r[3]=(__bf16)a.w;
    r[4]=(__bf16)b.x; r[5]=(__bf16)b.y; r[6]=(__bf16)b.z; r[7]=(__bf16)b.w;
    return r;
}

__device__ __forceinline__ void unpack8(const uint4& a, const uint4& b,
                                        bf16x8& h, bf16x8& l) {
    unsigned u[8] = {a.x, a.y, a.z, a.w, b.x, b.y, b.z, b.w};
    union { unsigned short s; __bf16 v; } t;
    #pragma unroll
    for (int i = 0; i < 8; i++) {
        t.s = (unsigned short)(u[i] & 0xffff); h[i] = t.v;
        t.s = (unsigned short)(u[i] >> 16);    l[i] = t.v;
    }
}
__device__ __forceinline__ bf16x8 unpack_hi8(const uint4& a, const uint4& b) {
    unsigned u[8] = {a.x, a.y, a.z, a.w, b.x, b.y, b.z, b.w};
    union { unsigned short s; __bf16 v; } t;
    bf16x8 h;
    #pragma unroll
    for (int i = 0; i < 8; i++) { t.s = (unsigned short)(u[i] & 0xffff); h[i] = t.v; }
    return h;
}

__device__ __forceinline__ unsigned pack_hilo(float x) {
    __bf16 hb = (__bf16)x;
    float hf = (float)hb;
    __bf16 lb = (__bf16)(x - hf);
    union { __bf16 b; unsigned short s; } ch, cl;
    ch.b = hb; cl.b = lb;
    return (unsigned)ch.s | ((unsigned)cl.s << 16);
}

__device__ __forceinline__ float fast_sigmoid(float x) {
    return 1.f / (1.f + __expf(-x));
}
__device__ __forceinline__ float fast_tanh(float x) {
    return 1.f - 2.f / (__expf(2.f * x) + 1.f);
}

// ---------------------------------------------------------------------------
// 1-pass bf16 GEMM (A hi, B hi): input projection (verified rounds 5/12).
// ---------------------------------------------------------------------------
__global__ __launch_bounds__(256) void gemm_ahi(
    const float* __restrict__ A, int lda,
    const float* __restrict__ B, int ldb,
    const float* __restrict__ bias,
    float* __restrict__ Z, int ldz,
    int N, int K)
{
    __shared__ __align__(16) char lds[32768];
    const int tid  = threadIdx.x;
    const int bm   = blockIdx.y * 128;
    const int bn   = blockIdx.x * 128;
    const int wave = tid >> 6;
    const int lane = tid & 63;
    const int wm   = (wave >> 1) * 64;
    const int wn   = (wave & 1) * 64;
    const int lr   = lane & 15;
    const int kg   = lane >> 4;

    const int rr = tid >> 4;
    const int kk = (tid & 15) * 4;

    f32x4 acc[4][4] = {};

    for (int k0 = 0; k0 < K; k0 += 64) {
        float4 av[8], bv[8];
        #pragma unroll
        for (int i = 0; i < 8; i++) {
            int r = i * 16 + rr;
            av[i] = *(const float4*)&A[(size_t)(bm + r) * lda + k0 + kk];
            int rb = bn + r;
            if (rb < N)
                bv[i] = *(const float4*)&B[(size_t)rb * ldb + k0 + kk];
            else
                bv[i] = make_float4(0.f, 0.f, 0.f, 0.f);
        }
        __syncthreads();
        #pragma unroll
        for (int i = 0; i < 8; i++) {
            int r = i * 16 + rr;
            int off = sw_off(r, kk);
            *(bf16x4*)(lds + off)         = hi4(av[i]);
            *(bf16x4*)(lds + 16384 + off) = hi4(bv[i]);
        }
        __syncthreads();
        #pragma unroll
        for (int ks = 0; ks < 2; ks++) {
            bf16x8 ah[4], bh[4];
            const int kbase = ks * 32 + kg * 8;
            #pragma unroll
            for (int f = 0; f < 4; f++) {
                ah[f] = *(const bf16x8*)(lds + sw_off(wm + f * 16 + lr, kbase));
                bh[f] = *(const bf16x8*)(lds + 16384 + sw_off(wn + f * 16 + lr, kbase));
            }
            #pragma unroll
            for (int fm = 0; fm < 4; fm++)
                #pragma unroll
                for (int fn = 0; fn < 4; fn++)
                    acc[fm][fn] = __builtin_amdgcn_mfma_f32_16x16x32_bf16(
                        ah[fm], bh[fn], acc[fm][fn], 0, 0, 0);
        }
        __syncthreads();
    }

    #pragma unroll
    for (int fn = 0; fn < 4; fn++) {
        int col = bn + wn + fn * 16 + lr;
        if (col < N) {
            float bb = bias ? bias[col] : 0.f;
            #pragma unroll
            for (int fm = 0; fm < 4; fm++) {
                #pragma unroll
                for (int j = 0; j < 4; j++) {
                    int row = bm + wm + fm * 16 + kg * 4 + j;
                    Z[(size_t)row * ldz + col] = acc[fm][fn][j] + bb;
                }
            }
        }
    }
}

// ---------------------------------------------------------------------------
// Vocab projection, 64-col panels, 2 blocks/CU (80 KB LDS):
// Z[1280][50257] = dec3h[1280][512](bf16) @ W_out^T + b_out.
// B panel [64][512] bf16 staged once (64 KB); A tile [128][64] bf16 per
// k-chunk (16 KB). 786 blocks -> 8 waves/CU latency hiding.
// ---------------------------------------------------------------------------
__global__ __launch_bounds__(256, 2) void gemm_vocab64(
    const __bf16* __restrict__ Ah,    // [1280][512] bf16
    const float* __restrict__ B,      // [50257][512] fp32
    const float* __restrict__ bias,   // [50257]
    float* __restrict__ Z)            // [1280][50257]
{
    __shared__ __align__(16) char lds[81920];   // B 64K | A 16K
    char* ldsB = lds;
    char* ldsA = lds + 65536;

    const int tid  = threadIdx.x;
    const int bn   = blockIdx.x * 64;
    const int wave = tid >> 6;
    const int lane = tid & 63;
    const int wm   = (wave >> 1) * 64;    // row half
    const int wn   = (wave & 1) * 32;     // col half
    const int lr   = lane & 15;
    const int kg   = lane >> 4;

    // ---- stage B panel once (fp32 -> bf16, swizzled) ----
    #pragma unroll 4
    for (int jj = 0; jj < 16; jj++) {
        int e = tid + jj * 256;           // 0..4095
        int row = e >> 6;                 // 0..63
        int k = (e & 63) * 8;             // 0..504
        int gr = bn + row;
        float4 v0, v1;
        if (gr < NTOK) {
            v0 = *(const float4*)&B[(size_t)gr * 512 + k];
            v1 = *(const float4*)&B[(size_t)gr * 512 + k + 4];
        } else {
            v0 = make_float4(0.f,0.f,0.f,0.f); v1 = v0;
        }
        *(bf16x8*)(ldsB + sw512(row, k)) = to_bf16x8(v0, v1);
    }

    float bb[2];
    #pragma unroll
    for (int fn = 0; fn < 2; fn++) {
        int col = bn + wn + fn * 16 + lr;
        bb[fn] = (col < NTOK) ? bias[col] : 0.f;
    }
    __syncthreads();

    for (int mt = 0; mt < 10; mt++) {
        f32x4 acc[4][2] = {};
        for (int k0 = 0; k0 < 8; k0++) {
            __syncthreads();   // WAR on A tile
            #pragma unroll
            for (int jj = 0; jj < 4; jj++) {
                int e = tid + jj * 256;       // 0..1023
                int row = e >> 3;             // 0..127
                int k = (e & 7) * 8;          // 0..56
                uint4 v = *(const uint4*)&Ah[(size_t)(mt * 128 + row) * 512 + k0 * 64 + k];
                *(uint4*)(ldsA + sw_off(row, k)) = v;
            }
            __syncthreads();
            #pragma unroll
            for (int ks = 0; ks < 2; ks++) {
                bf16x8 ah[4], bh[2];
                const int ka = ks * 32 + kg * 8;
                #pragma unroll
                for (int f = 0; f < 4; f++)
                    ah[f] = *(const bf16x8*)(ldsA + sw_off(wm + f * 16 + lr, ka));
                #pragma unroll
                for (int f = 0; f < 2; f++)
                    bh[f] = *(const bf16x8*)(ldsB + sw512(wn + f * 16 + lr, k0 * 64 + ka));
                #pragma unroll
                for (int fm = 0; fm < 4; fm++)
                    #pragma unroll
                    for (int fn = 0; fn < 2; fn++)
                        acc[fm][fn] = __builtin_amdgcn_mfma_f32_16x16x32_bf16(
                            ah[fm], bh[fn], acc[fm][fn], 0, 0, 0);
            }
        }
        #pragma unroll
        for (int fn = 0; fn < 2; fn++) {
            int col = bn + wn + fn * 16 + lr;
            if (col < NTOK) {
                #pragma unroll
                for (int fm = 0; fm < 4; fm++) {
                    #pragma unroll
                    for (int j = 0; j < 4; j++) {
                        int row = mt * 128 + wm + fm * 16 + kg * 4 + j;
                        Z[(size_t)row * NTOK + col] = acc[fm][fn][j] + bb[fn];
                    }
                }
            }
        }
    }
}

// ---------------------------------------------------------------------------
// Grid barrier (256 blocks, 1/CU co-resident): two-hop, single gen broadcast.
// (r5/r9/r12-proven; leader gather hard-spins)
// ---------------------------------------------------------------------------
__device__ __forceinline__ void grid_barrier(unsigned* flags, unsigned* gen,
                                             unsigned target)
{
    __syncthreads();
    if (threadIdx.x == 0) {
        __builtin_amdgcn_fence(__ATOMIC_RELEASE, "agent");
        __hip_atomic_store(&flags[blockIdx.x], target, __ATOMIC_RELAXED,
                           __HIP_MEMORY_SCOPE_AGENT);
    }
    if (blockIdx.x == 0) {
        while (__hip_atomic_load(&flags[threadIdx.x], __ATOMIC_RELAXED,
                                 __HIP_MEMORY_SCOPE_AGENT) < target)
            ;   // hard spin — leader only
        __syncthreads();
        if (threadIdx.x == 0)
            __hip_atomic_store(gen, target, __ATOMIC_RELAXED,
                               __HIP_MEMORY_SCOPE_AGENT);
    }
    if (threadIdx.x == 0) {
        while (__hip_atomic_load(gen, __ATOMIC_RELAXED,
                                 __HIP_MEMORY_SCOPE_AGENT) < target)
            __builtin_amdgcn_s_sleep(1);
        __builtin_amdgcn_fence(__ATOMIC_ACQUIRE, "agent");
    }
    __syncthreads();
}

// ---------------------------------------------------------------------------
// Fused 4-layer pipelined LSTM scan — round-12 version (best measured:
// 1209 us). Unchanged.
// ---------------------------------------------------------------------------
__global__ __launch_bounds__(256, 1) void fused_scan(
    const float* __restrict__ Zx,
    const float* __restrict__ Whh_0, const float* __restrict__ bias_0,
    const float* __restrict__ Wih_1, const float* __restrict__ Whh_1,
    const float* __restrict__ bias_1,
    const float* __restrict__ Wih_2, const float* __restrict__ Whh_2,
    const float* __restrict__ bias_2e, const float* __restrict__ bias_2d,
    const float* __restrict__ Wih_3, const float* __restrict__ Whh_3,
    const float* __restrict__ bias_3,
    const float* __restrict__ hid1_h, const float* __restrict__ hid1_c,
    const float* __restrict__ hid2_h, const float* __restrict__ hid2_c,
    __bf16* __restrict__ dec3h,
    unsigned* hbuf, unsigned* flags, unsigned* gen)
{
    __shared__ __align__(16) char lds[131072];
    float* a_x = (float*)(lds + 32768);   // aliases A_lo (restaged each step)

    const int tid  = threadIdx.x;
    const int L    = blockIdx.x >> 6;
    const int bidc = blockIdx.x & 63;
    const int wave = tid >> 6;
    const int lane = tid & 63;
    const int mh   = wave >> 1;
    const int nh   = wave & 1;
    const int lr   = lane & 15;
    const int kg   = lane >> 4;
    const int jcbase = bidc * 8;
    const int bq = tid >> 3;     // staging row 0..31
    const int aq = tid & 7;      // staging k-lane

    const float* Whh = (L==0)?Whh_0:(L==1)?Whh_1:(L==2)?Whh_2:Whh_3;
    const float* Wih = (L==1)?Wih_1:(L==2)?Wih_2:(L==3)?Wih_3:nullptr;
    const int ld_ih  = (L==2)?1024:512;
    const float* be  = (L==0)?bias_0:(L==1)?bias_1:(L==2)?bias_2e:bias_3;
    const float* bd  = (L==2)?bias_2d:be;
    const float* h0  = ((L<2)?hid1_h:hid2_h) + (L&1)*16384;
    const float* c0  = ((L<2)?hid1_c:hid2_c) + (L&1)*16384;
    unsigned* myb       = hbuf + L*32768;
    const unsigned* xsb = hbuf + (L>0 ? (L-1)*32768 : 0);

    // ---- stage weights hi-only, once ----
    {
        int gate = (bq<8)?0:(bq<16)?2:(bq<24)?1:3;   // rows: i,g,f,o
        int row  = gate*512 + jcbase + (bq&7);
        const float* wr = Whh + (size_t)row * 512;
        #pragma unroll
        for (int jj = 0; jj < 8; jj++) {
            int k = aq*8 + jj*64;
            *(bf16x8*)(lds + 65536 + sw512(bq, k)) =
                to_bf16x8(*(const float4*)(wr+k), *(const float4*)(wr+k+4));
        }
        if (Wih) {
            const float* wr2 = Wih + (size_t)row * ld_ih;
            #pragma unroll
            for (int jj = 0; jj < 8; jj++) {
                int k = aq*8 + jj*64;
                *(bf16x8*)(lds + 98304 + sw512(bq, k)) =
                    to_bf16x8(*(const float4*)(wr2+k), *(const float4*)(wr2+k+4));
            }
        }
    }

    // lane's output-column mapping
    const int n_col = nh*16 + lr;
    const int gate  = (n_col<8)?0:(n_col<16)?2:(n_col<24)?1:3;
    const int col2048 = gate*512 + jcbase + (n_col & 7);
    const float bbe = be[col2048];
    const float bbd = bd[col2048];

    // c state: nh==1, lr<8 lanes, 4 batches each
    float cc[4] = {0.f, 0.f, 0.f, 0.f};
    if (nh == 1 && lr < 8) {
        #pragma unroll
        for (int j = 0; j < 4; j++)
            cc[j] = c0[(mh*16 + kg*4 + j)*512 + jcbase + lr];
    }

    // ---- Zx prefetch for the first step (L0 only) ----
    float zxr[4] = {0.f, 0.f, 0.f, 0.f};
    if (L == 0) {
        #pragma unroll
        for (int j = 0; j < 4; j++)
            zxr[j] = Zx[(size_t)(mh*16 + kg*4 + j)*G4 + col2048];
    }
    __syncthreads();

    const int rowA = mh*16 + lr;
    const int rowB = nh*16 + lr;

    for (int tt = 0; tt < 123; ++tt) {
        const int myt = tt - L;
        if (myt >= 0 && myt < 120) {
            // ---- hoist x loads (L>=1) ----
            uint4 xr[8][2];
            if (L > 0) {
                const unsigned* xs = xsb + (size_t)(myt & 1)*16384 + bq*512;
                #pragma unroll
                for (int jj = 0; jj < 8; jj++) {
                    int k = aq*8 + jj*64;
                    xr[jj][0] = *(const uint4*)(xs + k);
                    xr[jj][1] = *(const uint4*)(xs + k + 4);
                }
            }
            // ---- stage h (hi/lo) ----
            if (myt == 0) {
                const float* hr = h0 + bq*512;
                #pragma unroll
                for (int jj = 0; jj < 8; jj++) {
                    int k = aq*8 + jj*64;
                    bf16x8 H, Lo;
                    split8(*(const float4*)(hr+k), *(const float4*)(hr+k+4), H, Lo);
                    int off = sw512(bq, k);
                    *(bf16x8*)(lds + off)         = H;
                    *(bf16x8*)(lds + 32768 + off) = Lo;
                }
            } else {
                const unsigned* hs = myb + (size_t)((myt-1) & 1)*16384 + bq*512;
                #pragma unroll
                for (int jj = 0; jj < 8; jj++) {
                    int k = aq*8 + jj*64;
                    bf16x8 H, Lo;
                    unpack8(*(const uint4*)(hs+k), *(const uint4*)(hs+k+4), H, Lo);
                    int off = sw512(bq, k);
                    *(bf16x8*)(lds + off)         = H;
                    *(bf16x8*)(lds + 32768 + off) = Lo;
                }
            }
            __syncthreads();

            // ---- phase 1: h @ Whh^T (2-pass, split accumulators) ----
            f32x4 accA = {0.f,0.f,0.f,0.f}, accB = {0.f,0.f,0.f,0.f};
            #pragma unroll
            for (int ks = 0; ks < 16; ++ks) {
                int k = ks*32 + kg*8;
                int offA = sw512(rowA, k);
                int offB = sw512(rowB, k);
                bf16x8 ah = *(const bf16x8*)(lds + offA);
                bf16x8 al = *(const bf16x8*)(lds + 32768 + offA);
                bf16x8 bh = *(const bf16x8*)(lds + 65536 + offB);
                accA = __builtin_amdgcn_mfma_f32_16x16x32_bf16(ah, bh, accA, 0,0,0);
                accB = __builtin_amdgcn_mfma_f32_16x16x32_bf16(al, bh, accB, 0,0,0);
            }
            __syncthreads();

            // ---- phase 2: x @ Wih^T (hi only) ----
            if (L > 0) {
                #pragma unroll
                for (int jj = 0; jj < 8; jj++) {
                    int k = aq*8 + jj*64;
                    *(bf16x8*)(lds + sw512(bq, k)) = unpack_hi8(xr[jj][0], xr[jj][1]);
                }
                __syncthreads();
                #pragma unroll
                for (int ks = 0; ks < 16; ++ks) {
                    int k = ks*32 + kg*8;
                    bf16x8 ax = *(const bf16x8*)(lds + sw512(rowA, k));
                    bf16x8 bi = *(const bf16x8*)(lds + 98304 + sw512(rowB, k));
                    accA = __builtin_amdgcn_mfma_f32_16x16x32_bf16(ax, bi, accA, 0,0,0);
                }
            }

            // ---- finalize z (uses prefetched zxr), then prefetch next Zx ----
            const float bbv = (L == 2 && myt >= 80) ? bbd : bbe;
            float z[4];
            #pragma unroll
            for (int j = 0; j < 4; j++)
                z[j] = accA[j] + accB[j] + bbv
                     + ((L == 0 && myt < 80) ? zxr[j] : 0.f);

            {
                int mytn = myt + 1;
                if (L == 0 && mytn < 80) {
                    #pragma unroll
                    for (int j = 0; j < 4; j++)
                        zxr[j] = Zx[(size_t)mytn*(BSZ*G4)
                                    + (mh*16+kg*4+j)*G4 + col2048];
                }
            }

            if (nh == 0) {
                // lr<8: z=i ; lr>=8: z=g -> a = sig(i)*tanh(g)
                float zo[4];
                #pragma unroll
                for (int j = 0; j < 4; j++) zo[j] = __shfl_xor(z[j], 8);
                if (lr < 8) {
                    #pragma unroll
                    for (int j = 0; j < 4; j++)
                        a_x[(mh*16 + kg*4 + j)*8 + lr] =
                            fast_sigmoid(z[j]) * fast_tanh(zo[j]);
                }
            }
            __syncthreads();

            if (nh == 1) {
                // lr<8: z=f ; lr>=8: z=o
                float cnew[4] = {0.f,0.f,0.f,0.f};
                if (lr < 8) {
                    #pragma unroll
                    for (int j = 0; j < 4; j++) {
                        float av = a_x[(mh*16 + kg*4 + j)*8 + lr];
                        cnew[j] = fast_sigmoid(z[j]) * cc[j] + av;
                        cc[j] = cnew[j];
                    }
                }
                float cfrom[4];
                #pragma unroll
                for (int j = 0; j < 4; j++) cfrom[j] = __shfl_xor(cnew[j], 8);
                if (lr >= 8) {
                    #pragma unroll
                    for (int j = 0; j < 4; j++) {
                        float hn = fast_sigmoid(z[j]) * fast_tanh(cfrom[j]);
                        int b = mh*16 + kg*4 + j;
                        int hcol = jcbase + (lr - 8);
                        if (L == 3 && myt >= 80)
                            dec3h[(size_t)(myt-80)*(BSZ*NHID) + b*512 + hcol] =
                                (__bf16)hn;
                        __hip_atomic_store(&myb[(size_t)(myt & 1)*16384 + b*512 + hcol],
                                           pack_hilo(hn), __ATOMIC_RELAXED,
                                           __HIP_MEMORY_SCOPE_AGENT);
                    }
                }
            }
        }
        grid_barrier(flags, gen, (unsigned)tt + 1u);
    }
}

// ---------------------------------------------------------------------------
// bias2[j] = l2_b0[j] + sum_h (W_emb[h*NTOK+0] + b_emb[h]) * Wih0[j*1024+h]
// ---------------------------------------------------------------------------
__global__ __launch_bounds__(256) void bias2_kernel(
    const float* __restrict__ W_emb,
    const float* __restrict__ b_emb,
    const float* __restrict__ Wih0,
    const float* __restrict__ b0,
    float* __restrict__ bias2)
{
    __shared__ float bos[NHID];
    const int tid = threadIdx.x;
    for (int i = tid; i < NHID; i += 256)
        bos[i] = W_emb[(size_t)i * NTOK] + b_emb[i];
    __syncthreads();
    int j = blockIdx.x * 256 + tid;
    float acc = b0[j];
    for (int k = 0; k < NHID; k++)
        acc += bos[k] * Wih0[(size_t)j * 1024 + k];
    bias2[j] = acc;
}

// ---------------------------------------------------------------------------
// In-place log_softmax over rows of 50257. float4-vectorized with per-row
// alignment peel (rows are 4B*1-misaligned: 50257 % 4 == 1); branchy online
// update (1 exp per element in the common case).
// ---------------------------------------------------------------------------
__global__ __launch_bounds__(256) void logsoftmax_kernel(float* __restrict__ logits)
{
    const size_t row = blockIdx.x;
    float* p = logits + row * (size_t)NTOK;
    const int tid = threadIdx.x;

    const int head = (int)((4 - (((size_t)row * NTOK) & 3)) & 3);
    const int nv   = (NTOK - head) >> 2;           // float4 count
    const int tail = head + nv * 4;
    float4* p4 = (float4*)(p + head);

    float m = -1e30f, s = 0.f;
    auto upd = [&](float x) {
        if (x <= m) {
            s += __expf(x - m);
        } else {
            s = s * __expf(m - x) + 1.f;
            m = x;
        }
    };

    for (int i = tid; i < head; i += 256) upd(p[i]);
    for (int i = tid; i < nv; i += 256) {
        float4 v = p4[i];
        upd(v.x); upd(v.y); upd(v.z); upd(v.w);
    }
    for (int i = tail + tid; i < NTOK; i += 256) upd(p[i]);

    // wave + block reduction (online merge)
    #pragma unroll
    for (int off = 32; off > 0; off >>= 1) {
        float mo = __shfl_down(m, off);
        float so = __shfl_down(s, off);
        float mn = fmaxf(m, mo);
        s = s * __expf(m - mn) + so * __expf(mo - mn);
        m = mn;
    }
    __shared__ float sm[4], ss[4];
    if ((tid & 63) == 0) { sm[tid >> 6] = m; ss[tid >> 6] = s; }
    __syncthreads();
    float M4 = fmaxf(fmaxf(sm[0], sm[1]), fmaxf(sm[2], sm[3]));
    float S  = ss[0] * __expf(sm[0] - M4) + ss[1] * __expf(sm[1] - M4)
             + ss[2] * __expf(sm[2] - M4) + ss[3] * __expf(sm[3] - M4);
    float lse = M4 + logf(S);

    for (int i = tid; i < head; i += 256) p[i] -= lse;
    for (int i = tid; i < nv; i += 256) {
        float4 v = p4[i];
        v.x -= lse; v.y -= lse; v.z -= lse; v.w -= lse;
        p4[i] = v;
    }
    for (int i = tail + tid; i < NTOK; i += 256) p[i] -= lse;
}

// ---------------------------------------------------------------------------
extern "C" void kernel_launch(void* const* d_in, const int* in_sizes, int n_in,
                              void* d_out, int out_size, void* d_ws, size_t ws_size,
                              hipStream_t stream)
{
    const float* inp     = (const float*)d_in[0];
    const float* hid1_h  = (const float*)d_in[1];
    const float* hid1_c  = (const float*)d_in[2];
    const float* hid2_h  = (const float*)d_in[3];
    const float* hid2_c  = (const float*)d_in[4];
    const float* l1_Wih0 = (const float*)d_in[5];
    const float* l1_Whh0 = (const float*)d_in[6];
    const float* l1_b0   = (const float*)d_in[7];
    const float* l1_Wih1 = (const float*)d_in[8];
    const float* l1_Whh1 = (const float*)d_in[9];
    const float* l1_b1   = (const float*)d_in[10];
    const float* l2_Wih0 = (const float*)d_in[11];
    const float* l2_Whh0 = (const float*)d_in[12];
    const float* l2_b0   = (const float*)d_in[13];
    const float* l2_Wih1 = (const float*)d_in[14];
    const float* l2_Whh1 = (const float*)d_in[15];
    const float* l2_b1   = (const float*)d_in[16];
    const float* W_out   = (const float*)d_in[17];
    const float* b_out   = (const float*)d_in[18];
    const float* W_emb   = (const float*)d_in[19];
    const float* b_emb   = (const float*)d_in[20];

    float* out = (float*)d_out;   // [40,32,50257]
    float* ws  = (float*)d_ws;

    // workspace layout (floats)
    float* Zx    = ws;                                  // [2560,2048]
    float* bias2 = ws + 5242880;                        // [2048]
    __bf16* dec3h = (__bf16*)(ws + 5244928);            // [1280][512] bf16
    unsigned* hbuf  = (unsigned*)(ws + 5572608);        // [4][2][16384] u32
    unsigned* flags = (unsigned*)(ws + 5703680);        // 256 + gen
    unsigned* gen   = flags + 256;

    (void)hipMemsetAsync(flags, 0, 1028, stream);

    // encoder lstm1 layer0 input projection (1-pass A-hi, B-hi)
    {
        dim3 grid((G4 + 127) / 128, (T_ENC * BSZ) / 128);
        gemm_ahi<<<grid, dim3(256), 0, stream>>>(
            inp, NINP, l1_Wih0, NINP, nullptr, Zx, G4, G4, NINP);
    }
    bias2_kernel<<<8, 256, 0, stream>>>(W_emb, b_emb, l2_Wih0, l2_b0, bias2);

    // fused pipelined scan: all 4 layers, encoder + decoder, one launch
    fused_scan<<<256, 256, 0, stream>>>(
        Zx,
        l1_Whh0, l1_b0,
        l1_Wih1, l1_Whh1, l1_b1,
        l2_Wih0 + 512, l2_Whh0, l2_b0, bias2,
        l2_Wih1, l2_Whh1, l2_b1,
        hid1_h, hid1_c, hid2_h, hid2_c,
        dec3h, hbuf, flags, gen);

    // vocab projection + log_softmax
    gemm_vocab64<<<(NTOK + 63) / 64, dim3(256), 0, stream>>>(
        dec3h, W_out, b_out, out);
    logsoftmax_kernel<<<1280, dim3(256), 0, stream>>>(out);
}